// Round 6
// baseline (359.283 us; speedup 1.0000x reference)
//
#include <hip/hip_runtime.h>
#include <hip/hip_fp16.h>
#include <cstdint>
#include <cstddef>

#define NQQ  (144*144)        // 20736
#define SCALE 0.17677669529663687f

// ws layout in HALF elements. Total 57,378,816 halves = 114.76 MiB.
// X16 (qkv-gemm input) and AO (attn output) share region 0 — X16 is dead
// before the attention kernel writes AO (strictly ordered on one stream).
#define AOH   0ull
#define X16H  0ull
#define QH    14155776ull
#define KH    28311552ull
#define VH    42467328ull
#define WTH   56623104ull      // 442368 halves (1152x384)
#define WOTH  57065472ull      // 147456 halves (384x384)
#define MASKH 57212928ull      // 165888 halves (8x144x144 fp16)

typedef _Float16 half8 __attribute__((ext_vector_type(8)));
typedef _Float16 half4v __attribute__((ext_vector_type(4)));
typedef float    f32x4 __attribute__((ext_vector_type(4)));

// ---------------------------------------------------------------------------
// PREP (one dispatch): [0,13824) convert X fp32->fp16; [13824,13932) transpose
// w_qkv; [13932,13968) transpose w_out; [13968,14130) convert mask fp32->fp16.
// ---------------------------------------------------------------------------
__launch_bounds__(256)
__global__ void k_prep(const float* __restrict__ X, _Float16* __restrict__ X16,
                       const float* __restrict__ Wq, _Float16* __restrict__ WqT,
                       const float* __restrict__ Wo, _Float16* __restrict__ WoT,
                       const float* __restrict__ M, _Float16* __restrict__ M16) {
    const int bid = blockIdx.x;
    const int t   = threadIdx.x;
    if (bid < 13824) {
        size_t i = (size_t)bid * 256 + t;
        float4 f = *(const float4*)&X[i * 4];
        _Float16 h[4] = {(_Float16)f.x, (_Float16)f.y, (_Float16)f.z, (_Float16)f.w};
        *(ushort4*)&X16[i * 4] = *(ushort4*)h;
        return;
    }
    if (bid >= 13968) {
        size_t i = (size_t)(bid - 13968) * 256 + t;
        float4 f = *(const float4*)&M[i * 4];
        _Float16 h[4] = {(_Float16)f.x, (_Float16)f.y, (_Float16)f.z, (_Float16)f.w};
        *(ushort4*)&M16[i * 4] = *(ushort4*)h;
        return;
    }
    __shared__ _Float16 sT[64][72];
    const float* W; _Float16* WT; int K, Cn, cb, kb;
    if (bid < 13932) {
        int j = bid - 13824;              // 108 tiles: 18 x 6
        W = Wq; WT = WqT; K = 384; Cn = 1152;
        cb = (j % 18) * 64; kb = (j / 18) * 64;
    } else {
        int j = bid - 13932;              // 36 tiles: 6 x 6
        W = Wo; WT = WoT; K = 384; Cn = 384;
        cb = (j % 6) * 64; kb = (j / 6) * 64;
    }
#pragma unroll
    for (int i = 0; i < 16; ++i) {
        int id = t + 256 * i;
        int kl = id >> 6, cl = id & 63;
        sT[cl][kl] = (_Float16)W[(size_t)(kb + kl) * Cn + cb + cl];
    }
    __syncthreads();
#pragma unroll
    for (int i = 0; i < 16; ++i) {
        int id = t + 256 * i;
        int cl = id >> 6, kl = id & 63;
        WT[(size_t)(cb + cl) * K + kb + kl] = sT[cl][kl];
    }
}

// ---------------------------------------------------------------------------
// K1: qkv = X16 @ WT^T (+bias, scale q) -> scatter fp16 [bh][n][d].
// ---------------------------------------------------------------------------
__launch_bounds__(256)
__global__ void k_qkv_gemm_mfma(const _Float16* __restrict__ X16,
                                const _Float16* __restrict__ WT,
                                const float* __restrict__ bq,
                                _Float16* __restrict__ ws16) {
    __shared__ _Float16 sA[128][40];
    __shared__ _Float16 sBT[128][40];
    const int t    = threadIdx.x;
    const int lane = t & 63;
    const int w    = t >> 6;
    const int quad = lane >> 4;
    const int l15  = lane & 15;
    const int r0   = blockIdx.x * 128, c0 = blockIdx.y * 128;
    const int wr   = (w >> 1) * 64, wc = (w & 1) * 64;

    f32x4 acc[4][4] = {};

    for (int kk = 0; kk < 384; kk += 32) {
#pragma unroll
        for (int i = 0; i < 2; ++i) {
            int id  = t + 256 * i;
            int row = id >> 2;
            int ko  = (id & 3) * 8;
            *(uint4*)&sA[row][ko]  = *(const uint4*)&X16[(size_t)(r0 + row) * 384 + kk + ko];
            *(uint4*)&sBT[row][ko] = *(const uint4*)&WT[(size_t)(c0 + row) * 384 + kk + ko];
        }
        __syncthreads();
        half8 a[4], b[4];
#pragma unroll
        for (int i = 0; i < 4; ++i) a[i] = *(const half8*)&sA[wr + 16 * i + l15][quad * 8];
#pragma unroll
        for (int j = 0; j < 4; ++j) b[j] = *(const half8*)&sBT[wc + 16 * j + l15][quad * 8];
#pragma unroll
        for (int i = 0; i < 4; ++i)
#pragma unroll
            for (int j = 0; j < 4; ++j)
                acc[i][j] = __builtin_amdgcn_mfma_f32_16x16x32_f16(a[i], b[j], acc[i][j], 0, 0, 0);
        __syncthreads();
    }

#pragma unroll
    for (int j = 0; j < 4; ++j) {
        int c  = c0 + wc + 16 * j + l15;
        int p  = c / 384;
        int hh = (c >> 5) % 12;
        int d0 = c & 31;
        float bias = bq[c];
        float sc   = (p == 0) ? SCALE : 1.0f;
        size_t base = (p == 0) ? QH : ((p == 1) ? KH : VH);
#pragma unroll
        for (int i = 0; i < 4; ++i) {
#pragma unroll
            for (int reg = 0; reg < 4; ++reg) {
                int r  = r0 + wr + 16 * i + quad * 4 + reg;
                int bw = r / 144;
                int n  = r - bw * 144;
                ws16[base + (((size_t)bw * 12 + hh) * 144 + n) * 32 + d0] =
                    (_Float16)((acc[i][j][reg] + bias) * sc);
            }
        }
    }
}

// ---------------------------------------------------------------------------
// K2: MFMA attention. One (b,h) per block, 576 threads = 9 waves; wave w owns
// q-tile w. ALL long-latency loads batched in phase 1 (K,V^T,mask fp16,bias
// gather -> LDS; Q fragment direct from global). Phase 3 softmax is pure LDS.
// sMask unions sP (wave w reads mask only from its own 16 rows, then writes P
// to those same rows after all its reads -> no barrier). ONE barrier total.
// LDS: sPM[144][168] 48384 + sVT[32][168] 10752 + sK[144][40] 11520 +
//      sBias16 5184 = 75840 B -> 2 blocks/CU, 18 waves/CU.
// ---------------------------------------------------------------------------
__launch_bounds__(576)
__global__ void k_attn_fused_mfma(const _Float16* __restrict__ ws16,
                                  const _Float16* __restrict__ mask16,
                                  const float* __restrict__ table,
                                  const int* __restrict__ pidx,
                                  _Float16* __restrict__ AO) {
    __shared__ __align__(16) char smem[75840];
    _Float16 (*sPM)[168] = (_Float16(*)[168])(smem);            // mask, then P
    _Float16 (*sVT)[168] = (_Float16(*)[168])(smem + 48384);
    _Float16 (*sK)[40]   = (_Float16(*)[40])(smem + 59136);
    _Float16* sBias      = (_Float16*)(smem + 70656);

    const int bh = blockIdx.x;
    const int b  = bh / 12;
    const int h  = bh - b * 12;
    const int t  = threadIdx.x;
    const int w    = t >> 6;        // 0..8 : q-tile index
    const int lane = t & 63;
    const int quad = lane >> 4;
    const int l15  = lane & 15;

    const int s_tile = b >> 5;
    const int i1     = b & 31;

    // --- phase 1: batch ALL global latency here ---
    const _Float16* qg = ws16 + QH + (size_t)bh * 4608;
    const _Float16* kg = ws16 + KH + (size_t)bh * 4608;
    const _Float16* vg = ws16 + VH + (size_t)bh * 4608;
    const _Float16* mg = mask16 + (size_t)(b & 7) * NQQ;

    half8 aq = *(const half8*)&qg[(size_t)(16 * w + l15) * 32 + quad * 8];

    {   // K: one uint4 per thread
        int row = t >> 2, ko = (t & 3) * 8;
        *(uint4*)&sK[row][ko] = *(const uint4*)&kg[row * 32 + ko];
    }
    for (int i = t; i < 2304; i += 576) {          // V -> V^T
        unsigned int u = ((const unsigned int*)vg)[i];
        int m = i >> 4, d0 = (i & 15) * 2;
        sVT[d0][m]     = ((const _Float16*)&u)[0];
        sVT[d0 + 1][m] = ((const _Float16*)&u)[1];
    }
    if (t < 512) {                                 // V^T zero-pad cols 144..159
        int d = t & 31, m = 144 + (t >> 5);
        sVT[d][m] = (_Float16)0;
    }
    for (int i = t; i < 5184; i += 576) {          // mask tile: 4-half chunks
        int row = i / 36, c4 = (i - row * 36) * 4;
        *(uint2*)&sPM[row][c4] = *(const uint2*)&mg[row * 144 + c4];
    }
    for (int i = t; i < 2592; i += 576) {          // bias gather (fp16 store)
        int row = pidx[8 * i + s_tile];
        sBias[i] = (_Float16)table[(size_t)row * 384 + i1 * 12 + h];
    }
    __syncthreads();   // the ONLY barrier

    // --- phase 2: S-tile = Q-tile @ K^T (9 col-tiles) ---
    half8 bk[9];
#pragma unroll
    for (int j = 0; j < 9; ++j) bk[j] = *(const half8*)&sK[16 * j + l15][quad * 8];
    f32x4 s[9] = {};
#pragma unroll
    for (int j = 0; j < 9; ++j)
        s[j] = __builtin_amdgcn_mfma_f32_16x16x32_f16(aq, bk[j], s[j], 0, 0, 0);

    // --- phase 3: bias + mask (both LDS) + softmax ; P overwrites own rows ---
    {
        const int nb = 16 * w + quad * 4;
        float sv[4][9];
#pragma unroll
        for (int reg = 0; reg < 4; ++reg) {
            int n  = nb + reg;
            int bo = (n % 18) * 144 + l15;
#pragma unroll
            for (int j = 0; j < 9; ++j)
                sv[reg][j] = s[j][reg] + (float)sBias[bo + 16 * j]
                                       + (float)sPM[n][16 * j + l15];
        }
#pragma unroll
        for (int reg = 0; reg < 4; ++reg) {
            float rmax = sv[reg][0];
#pragma unroll
            for (int j = 1; j < 9; ++j) rmax = fmaxf(rmax, sv[reg][j]);
            for (int off = 1; off < 16; off <<= 1)
                rmax = fmaxf(rmax, __shfl_xor(rmax, off, 16));
            float rsum = 0.0f;
#pragma unroll
            for (int j = 0; j < 9; ++j) { sv[reg][j] = __expf(sv[reg][j] - rmax); rsum += sv[reg][j]; }
            for (int off = 1; off < 16; off <<= 1)
                rsum += __shfl_xor(rsum, off, 16);
            float inv = 1.0f / rsum;
            int n = nb + reg;
#pragma unroll
            for (int j = 0; j < 9; ++j)
                sPM[n][16 * j + l15] = (_Float16)(sv[reg][j] * inv);
        }
    }
    // zero-pad own rows' cols 144..159
    for (int i = lane; i < 256; i += 64)
        sPM[16 * w + (i >> 4)][144 + (i & 15)] = (_Float16)0;

    // --- phase 4: O^T-tile = V^T @ P^T (own rows only; wave-local) ---
    f32x4 o[2] = {};
#pragma unroll
    for (int kt = 0; kt < 5; ++kt) {
        half8 bp = *(const half8*)&sPM[16 * w + l15][kt * 32 + quad * 8];
#pragma unroll
        for (int dt = 0; dt < 2; ++dt) {
            half8 av = *(const half8*)&sVT[dt * 16 + l15][kt * 32 + quad * 8];
            o[dt] = __builtin_amdgcn_mfma_f32_16x16x32_f16(av, bp, o[dt], 0, 0, 0);
        }
    }

    // --- stores: O^T[d][q] -> AO[b][q][h*32+d] ---
#pragma unroll
    for (int dt = 0; dt < 2; ++dt) {
        int q = 16 * w + l15;
        int d = dt * 16 + quad * 4;
        half4v hv;
#pragma unroll
        for (int reg = 0; reg < 4; ++reg) hv[reg] = (_Float16)o[dt][reg];
        *(half4v*)&AO[((size_t)b * 144 + q) * 384 + h * 32 + d] = hv;
    }
}

// ---------------------------------------------------------------------------
// K3: out = AO @ WoT^T + b_out. fp32 output.
// ---------------------------------------------------------------------------
__launch_bounds__(256)
__global__ void k_out_gemm_mfma(const _Float16* __restrict__ A16,
                                const _Float16* __restrict__ WoT,
                                const float* __restrict__ bo,
                                float* __restrict__ out) {
    __shared__ _Float16 sA[128][40];
    __shared__ _Float16 sBT[128][40];
    const int t    = threadIdx.x;
    const int lane = t & 63;
    const int w    = t >> 6;
    const int quad = lane >> 4;
    const int l15  = lane & 15;
    const int r0   = blockIdx.x * 128, c0 = blockIdx.y * 128;
    const int wr   = (w >> 1) * 64, wc = (w & 1) * 64;

    f32x4 acc[4][4] = {};

    for (int kk = 0; kk < 384; kk += 32) {
#pragma unroll
        for (int i = 0; i < 2; ++i) {
            int id  = t + 256 * i;
            int row = id >> 2;
            int ko  = (id & 3) * 8;
            *(uint4*)&sA[row][ko]  = *(const uint4*)&A16[(size_t)(r0 + row) * 384 + kk + ko];
            *(uint4*)&sBT[row][ko] = *(const uint4*)&WoT[(size_t)(c0 + row) * 384 + kk + ko];
        }
        __syncthreads();
        half8 a[4], b[4];
#pragma unroll
        for (int i = 0; i < 4; ++i) a[i] = *(const half8*)&sA[wr + 16 * i + l15][quad * 8];
#pragma unroll
        for (int j = 0; j < 4; ++j) b[j] = *(const half8*)&sBT[wc + 16 * j + l15][quad * 8];
#pragma unroll
        for (int i = 0; i < 4; ++i)
#pragma unroll
            for (int j = 0; j < 4; ++j)
                acc[i][j] = __builtin_amdgcn_mfma_f32_16x16x32_f16(a[i], b[j], acc[i][j], 0, 0, 0);
        __syncthreads();
    }

#pragma unroll
    for (int j = 0; j < 4; ++j) {
        int c = c0 + wc + 16 * j + l15;
        float bias = bo[c];
#pragma unroll
        for (int i = 0; i < 4; ++i) {
#pragma unroll
            for (int reg = 0; reg < 4; ++reg) {
                int r = r0 + wr + 16 * i + quad * 4 + reg;
                out[(size_t)r * 384 + c] = acc[i][j][reg] + bias;
            }
        }
    }
}

// ---------------------------------------------------------------------------
extern "C" void kernel_launch(void* const* d_in, const int* in_sizes, int n_in,
                              void* d_out, int out_size, void* d_ws, size_t ws_size,
                              hipStream_t stream) {
    const float* x      = (const float*)d_in[0];
    const float* mask   = (const float*)d_in[1];
    const float* w_qkv  = (const float*)d_in[2];
    const float* b_qkv  = (const float*)d_in[3];
    const float* w_out  = (const float*)d_in[4];
    const float* b_out  = (const float*)d_in[5];
    const float* table  = (const float*)d_in[6];
    const int*   pidx   = (const int*)d_in[7];
    float* out = (float*)d_out;
    _Float16* ws16 = (_Float16*)d_ws;

    hipLaunchKernelGGL(k_prep,          dim3(14130), dim3(256), 0, stream,
                       x, ws16 + X16H, w_qkv, ws16 + WTH, w_out, ws16 + WOTH,
                       mask, ws16 + MASKH);
    hipLaunchKernelGGL(k_qkv_gemm_mfma, dim3(288, 9), dim3(256), 0, stream,
                       ws16 + X16H, ws16 + WTH, b_qkv, ws16);
    hipLaunchKernelGGL(k_attn_fused_mfma, dim3(3072), dim3(576), 0, stream,
                       ws16, ws16 + MASKH, table, pidx, ws16 + AOH);
    hipLaunchKernelGGL(k_out_gemm_mfma, dim3(288, 3), dim3(256), 0, stream,
                       ws16 + AOH, ws16 + WOTH, b_out, out);
}

// Round 8
// 316.200 us; speedup vs baseline: 1.1363x; 1.1363x over previous
//
#include <hip/hip_runtime.h>
#include <hip/hip_fp16.h>
#include <cstdint>
#include <cstddef>

#define NQQ  (144*144)        // 20736
#define SCALE 0.17677669529663687f

// ws layout in HALF elements. Total 57,378,816 halves = 114.76 MiB.
#define AOH   0ull
#define X16H  0ull
#define QH    14155776ull
#define KH    28311552ull
#define VH    42467328ull
#define WTH   56623104ull      // 442368 halves (1152x384)
#define WOTH  57065472ull      // 147456 halves (384x384)
#define MASKH 57212928ull      // 165888 halves (8x144x144 fp16)

typedef _Float16 half8  __attribute__((ext_vector_type(8)));
typedef _Float16 half4v __attribute__((ext_vector_type(4)));
typedef float    f32x4  __attribute__((ext_vector_type(4)));

// ---------------------------------------------------------------------------
// PREP: [0,13824) X fp32->fp16; [13824,13932) transpose w_qkv;
// [13932,13968) transpose w_out; [13968,14130) mask fp32->fp16.
// ---------------------------------------------------------------------------
__launch_bounds__(256)
__global__ void k_prep(const float* __restrict__ X, _Float16* __restrict__ X16,
                       const float* __restrict__ Wq, _Float16* __restrict__ WqT,
                       const float* __restrict__ Wo, _Float16* __restrict__ WoT,
                       const float* __restrict__ M, _Float16* __restrict__ M16) {
    const int bid = blockIdx.x;
    const int t   = threadIdx.x;
    if (bid < 13824) {
        size_t i = (size_t)bid * 256 + t;
        float4 f = *(const float4*)&X[i * 4];
        _Float16 h[4] = {(_Float16)f.x, (_Float16)f.y, (_Float16)f.z, (_Float16)f.w};
        *(ushort4*)&X16[i * 4] = *(ushort4*)h;
        return;
    }
    if (bid >= 13968) {
        size_t i = (size_t)(bid - 13968) * 256 + t;
        float4 f = *(const float4*)&M[i * 4];
        _Float16 h[4] = {(_Float16)f.x, (_Float16)f.y, (_Float16)f.z, (_Float16)f.w};
        *(ushort4*)&M16[i * 4] = *(ushort4*)h;
        return;
    }
    __shared__ _Float16 sT[64][72];
    const float* W; _Float16* WT; int K, Cn, cb, kb;
    if (bid < 13932) {
        int j = bid - 13824;
        W = Wq; WT = WqT; K = 384; Cn = 1152;
        cb = (j % 18) * 64; kb = (j / 18) * 64;
    } else {
        int j = bid - 13932;
        W = Wo; WT = WoT; K = 384; Cn = 384;
        cb = (j % 6) * 64; kb = (j / 6) * 64;
    }
#pragma unroll
    for (int i = 0; i < 16; ++i) {
        int id = t + 256 * i;
        int kl = id >> 6, cl = id & 63;
        sT[cl][kl] = (_Float16)W[(size_t)(kb + kl) * Cn + cb + cl];
    }
    __syncthreads();
#pragma unroll
    for (int i = 0; i < 16; ++i) {
        int id = t + 256 * i;
        int cl = id >> 6, kl = id & 63;
        WT[(size_t)(cb + cl) * K + kb + kl] = sT[cl][kl];
    }
}

// ---------------------------------------------------------------------------
// K1: qkv = X16 @ WT^T (+bias, scale q) -> scatter fp16 [bh][n][d].
// ---------------------------------------------------------------------------
__launch_bounds__(256)
__global__ void k_qkv_gemm_mfma(const _Float16* __restrict__ X16,
                                const _Float16* __restrict__ WT,
                                const float* __restrict__ bq,
                                _Float16* __restrict__ ws16) {
    __shared__ _Float16 sA[128][40];
    __shared__ _Float16 sBT[128][40];
    const int t    = threadIdx.x;
    const int lane = t & 63;
    const int w    = t >> 6;
    const int quad = lane >> 4;
    const int l15  = lane & 15;
    const int r0   = blockIdx.x * 128, c0 = blockIdx.y * 128;
    const int wr   = (w >> 1) * 64, wc = (w & 1) * 64;

    f32x4 acc[4][4] = {};

    for (int kk = 0; kk < 384; kk += 32) {
#pragma unroll
        for (int i = 0; i < 2; ++i) {
            int id  = t + 256 * i;
            int row = id >> 2;
            int ko  = (id & 3) * 8;
            *(uint4*)&sA[row][ko]  = *(const uint4*)&X16[(size_t)(r0 + row) * 384 + kk + ko];
            *(uint4*)&sBT[row][ko] = *(const uint4*)&WT[(size_t)(c0 + row) * 384 + kk + ko];
        }
        __syncthreads();
        half8 a[4], b[4];
#pragma unroll
        for (int i = 0; i < 4; ++i) a[i] = *(const half8*)&sA[wr + 16 * i + l15][quad * 8];
#pragma unroll
        for (int j = 0; j < 4; ++j) b[j] = *(const half8*)&sBT[wc + 16 * j + l15][quad * 8];
#pragma unroll
        for (int i = 0; i < 4; ++i)
#pragma unroll
            for (int j = 0; j < 4; ++j)
                acc[i][j] = __builtin_amdgcn_mfma_f32_16x16x32_f16(a[i], b[j], acc[i][j], 0, 0, 0);
        __syncthreads();
    }

#pragma unroll
    for (int j = 0; j < 4; ++j) {
        int c  = c0 + wc + 16 * j + l15;
        int p  = c / 384;
        int hh = (c >> 5) % 12;
        int d0 = c & 31;
        float bias = bq[c];
        float sc   = (p == 0) ? SCALE : 1.0f;
        size_t base = (p == 0) ? QH : ((p == 1) ? KH : VH);
#pragma unroll
        for (int i = 0; i < 4; ++i) {
#pragma unroll
            for (int reg = 0; reg < 4; ++reg) {
                int r  = r0 + wr + 16 * i + quad * 4 + reg;
                int bw = r / 144;
                int n  = r - bw * 144;
                ws16[base + (((size_t)bw * 12 + hh) * 144 + n) * 32 + d0] =
                    (_Float16)((acc[i][j][reg] + bias) * sc);
            }
        }
    }
}

// ---------------------------------------------------------------------------
// K2: MFMA attention, S^T formulation — NO P round-trip through LDS.
// One (b,h) per block, 576 threads = 9 waves; wave w owns q-tile w.
// Phase 2: T_j = mfma(K_j, Q_w) = S^T tile (lane: key=16j+quad*4+reg, qry=l15).
// Phase 3: bias(LDS)+mask(global fp16)+softmax; reduction across quads =
//          shfl_xor(16,32). P^T stays in registers (packed fp16).
// Phase 4: B-fragments of P^T built by __shfl: target (quad,l15) takes regs
//          0..3 of tile 2kt+(quad>>1) from lanes 32*(quad&1)+l15 and +16.
// LDS: sK 11520 + sVT 10752 + sBias 5184 = 27456 B. ONE barrier, ZERO LDS
// writes after phase 1.
// ---------------------------------------------------------------------------
__launch_bounds__(576)
__global__ void k_attn_fused_mfma(const _Float16* __restrict__ ws16,
                                  const _Float16* __restrict__ mask16,
                                  const float* __restrict__ table,
                                  const int* __restrict__ pidx,
                                  _Float16* __restrict__ AO) {
    __shared__ __align__(16) char smem[27456];
    _Float16 (*sK)[40]   = (_Float16(*)[40])(smem);             // 11520
    _Float16 (*sVT)[168] = (_Float16(*)[168])(smem + 11520);    // 10752
    _Float16* sBias      = (_Float16*)(smem + 22272);           // 5184

    const int bh = blockIdx.x;
    const int b  = bh / 12;
    const int h  = bh - b * 12;
    const int t  = threadIdx.x;
    const int w    = t >> 6;        // 0..8 : q-tile index
    const int lane = t & 63;
    const int quad = lane >> 4;
    const int l15  = lane & 15;

    const int s_tile = b >> 5;
    const int i1     = b & 31;

    // --- phase 1: loads ---
    const _Float16* qg = ws16 + QH + (size_t)bh * 4608;
    const _Float16* kg = ws16 + KH + (size_t)bh * 4608;
    const _Float16* vg = ws16 + VH + (size_t)bh * 4608;

    half8 aq = *(const half8*)&qg[(size_t)(16 * w + l15) * 32 + quad * 8];

    {   // K: one uint4 per thread (144 rows x 4 chunks = 576)
        int row = t >> 2, ko = (t & 3) * 8;
        *(uint4*)&sK[row][ko] = *(const uint4*)&kg[row * 32 + ko];
    }
    for (int i = t; i < 2304; i += 576) {          // V -> V^T
        unsigned int u = ((const unsigned int*)vg)[i];
        int m = i >> 4, d0 = (i & 15) * 2;
        sVT[d0][m]     = ((const _Float16*)&u)[0];
        sVT[d0 + 1][m] = ((const _Float16*)&u)[1];
    }
    if (t < 512) {                                 // V^T zero-pad cols 144..159
        int d = t & 31, m = 144 + (t >> 5);
        sVT[d][m] = (_Float16)0;
    }
    for (int i = t; i < 2592; i += 576) {          // bias gather (fp16)
        int row = pidx[8 * i + s_tile];
        sBias[i] = (_Float16)table[(size_t)row * 384 + i1 * 12 + h];
    }
    __syncthreads();   // the ONLY barrier

    // --- phase 2: T_j = S^T tiles = mfma(K_j, Q_w) ---
    f32x4 tj[9] = {};
#pragma unroll
    for (int j = 0; j < 9; ++j) {
        half8 bk = *(const half8*)&sK[16 * j + l15][quad * 8];
        tj[j] = __builtin_amdgcn_mfma_f32_16x16x32_f16(bk, aq, tj[j], 0, 0, 0);
    }

    // --- phase 3: bias + mask + softmax over each query column ---
    const int q    = 16 * w + l15;                 // this lane's query row
    const int nb18 = q % 18;
    const _Float16* mrow = mask16 + (size_t)(b & 7) * NQQ + (size_t)q * 144 + 4 * quad;
    uint2 mz[9];
#pragma unroll
    for (int j = 0; j < 9; ++j) mz[j] = *(const uint2*)&mrow[16 * j];
#pragma unroll
    for (int j = 0; j < 9; ++j) {
        uint2 bz = *(const uint2*)&sBias[nb18 * 144 + 16 * j + 4 * quad];
        const _Float16* bb = (const _Float16*)&bz;
        const _Float16* mm = (const _Float16*)&mz[j];
#pragma unroll
        for (int reg = 0; reg < 4; ++reg)
            tj[j][reg] += (float)bb[reg] + (float)mm[reg];
    }
    float rmax = tj[0][0];
#pragma unroll
    for (int j = 0; j < 9; ++j)
#pragma unroll
        for (int reg = 0; reg < 4; ++reg) rmax = fmaxf(rmax, tj[j][reg]);
    rmax = fmaxf(rmax, __shfl_xor(rmax, 16));
    rmax = fmaxf(rmax, __shfl_xor(rmax, 32));
    float rsum = 0.0f;
#pragma unroll
    for (int j = 0; j < 9; ++j)
#pragma unroll
        for (int reg = 0; reg < 4; ++reg) {
            tj[j][reg] = __expf(tj[j][reg] - rmax);
            rsum += tj[j][reg];
        }
    rsum += __shfl_xor(rsum, 16);
    rsum += __shfl_xor(rsum, 32);
    const float inv = 1.0f / rsum;

    // pack P^T rows (scaled) to fp16 pairs; index 9 = zero pad (keys 144..159)
    unsigned int pkA[10], pkB[10];
    pkA[9] = 0u; pkB[9] = 0u;
#pragma unroll
    for (int j = 0; j < 9; ++j) {
        auto a2 = __builtin_amdgcn_cvt_pkrtz(tj[j][0] * inv, tj[j][1] * inv);
        auto b2 = __builtin_amdgcn_cvt_pkrtz(tj[j][2] * inv, tj[j][3] * inv);
        pkA[j] = *(unsigned int*)&a2;
        pkB[j] = *(unsigned int*)&b2;
    }

    // --- phase 4: O^T = V^T @ P^T ; P^T B-frags via cross-lane shuffles ---
    const int src_lo = 32 * (quad & 1) + l15;
    const int src_hi = src_lo + 16;
    const bool selhi = (quad >> 1) != 0;
    f32x4 o[2] = {};
#pragma unroll
    for (int kt = 0; kt < 5; ++kt) {
        const int j0 = 2 * kt, j1 = 2 * kt + 1;
        unsigned int a0l = __shfl((int)pkA[j0], src_lo);
        unsigned int a1l = __shfl((int)pkA[j1], src_lo);
        unsigned int b0l = __shfl((int)pkB[j0], src_lo);
        unsigned int b1l = __shfl((int)pkB[j1], src_lo);
        unsigned int a0h = __shfl((int)pkA[j0], src_hi);
        unsigned int a1h = __shfl((int)pkA[j1], src_hi);
        unsigned int b0h = __shfl((int)pkB[j0], src_hi);
        unsigned int b1h = __shfl((int)pkB[j1], src_hi);
        union { uint4 u4; half8 h8; } bp;
        bp.u4.x = selhi ? a1l : a0l;
        bp.u4.y = selhi ? b1l : b0l;
        bp.u4.z = selhi ? a1h : a0h;
        bp.u4.w = selhi ? b1h : b0h;
#pragma unroll
        for (int dt = 0; dt < 2; ++dt) {
            half8 av = *(const half8*)&sVT[dt * 16 + l15][kt * 32 + quad * 8];
            o[dt] = __builtin_amdgcn_mfma_f32_16x16x32_f16(av, bp.h8, o[dt], 0, 0, 0);
        }
    }

    // --- stores: O^T[d][q] -> AO[b][q][h*32+d] ---
#pragma unroll
    for (int dt = 0; dt < 2; ++dt) {
        int d = dt * 16 + quad * 4;
        half4v hv;
#pragma unroll
        for (int reg = 0; reg < 4; ++reg) hv[reg] = (_Float16)o[dt][reg];
        *(half4v*)&AO[((size_t)b * 144 + q) * 384 + h * 32 + d] = hv;
    }
}

// ---------------------------------------------------------------------------
// K3: out = AO @ WoT^T + b_out. fp32 output.
// ---------------------------------------------------------------------------
__launch_bounds__(256)
__global__ void k_out_gemm_mfma(const _Float16* __restrict__ A16,
                                const _Float16* __restrict__ WoT,
                                const float* __restrict__ bo,
                                float* __restrict__ out) {
    __shared__ _Float16 sA[128][40];
    __shared__ _Float16 sBT[128][40];
    const int t    = threadIdx.x;
    const int lane = t & 63;
    const int w    = t >> 6;
    const int quad = lane >> 4;
    const int l15  = lane & 15;
    const int r0   = blockIdx.x * 128, c0 = blockIdx.y * 128;
    const int wr   = (w >> 1) * 64, wc = (w & 1) * 64;

    f32x4 acc[4][4] = {};

    for (int kk = 0; kk < 384; kk += 32) {
#pragma unroll
        for (int i = 0; i < 2; ++i) {
            int id  = t + 256 * i;
            int row = id >> 2;
            int ko  = (id & 3) * 8;
            *(uint4*)&sA[row][ko]  = *(const uint4*)&A16[(size_t)(r0 + row) * 384 + kk + ko];
            *(uint4*)&sBT[row][ko] = *(const uint4*)&WoT[(size_t)(c0 + row) * 384 + kk + ko];
        }
        __syncthreads();
        half8 a[4], b[4];
#pragma unroll
        for (int i = 0; i < 4; ++i) a[i] = *(const half8*)&sA[wr + 16 * i + l15][quad * 8];
#pragma unroll
        for (int j = 0; j < 4; ++j) b[j] = *(const half8*)&sBT[wc + 16 * j + l15][quad * 8];
#pragma unroll
        for (int i = 0; i < 4; ++i)
#pragma unroll
            for (int j = 0; j < 4; ++j)
                acc[i][j] = __builtin_amdgcn_mfma_f32_16x16x32_f16(a[i], b[j], acc[i][j], 0, 0, 0);
        __syncthreads();
    }

#pragma unroll
    for (int j = 0; j < 4; ++j) {
        int c = c0 + wc + 16 * j + l15;
        float bias = bo[c];
#pragma unroll
        for (int i = 0; i < 4; ++i) {
#pragma unroll
            for (int reg = 0; reg < 4; ++reg) {
                int r = r0 + wr + 16 * i + quad * 4 + reg;
                out[(size_t)r * 384 + c] = acc[i][j][reg] + bias;
            }
        }
    }
}

// ---------------------------------------------------------------------------
extern "C" void kernel_launch(void* const* d_in, const int* in_sizes, int n_in,
                              void* d_out, int out_size, void* d_ws, size_t ws_size,
                              hipStream_t stream) {
    const float* x      = (const float*)d_in[0];
    const float* mask   = (const float*)d_in[1];
    const float* w_qkv  = (const float*)d_in[2];
    const float* b_qkv  = (const float*)d_in[3];
    const float* w_out  = (const float*)d_in[4];
    const float* b_out  = (const float*)d_in[5];
    const float* table  = (const float*)d_in[6];
    const int*   pidx   = (const int*)d_in[7];
    float* out = (float*)d_out;
    _Float16* ws16 = (_Float16*)d_ws;

    hipLaunchKernelGGL(k_prep,          dim3(14130), dim3(256), 0, stream,
                       x, ws16 + X16H, w_qkv, ws16 + WTH, w_out, ws16 + WOTH,
                       mask, ws16 + MASKH);
    hipLaunchKernelGGL(k_qkv_gemm_mfma, dim3(288, 9), dim3(256), 0, stream,
                       ws16 + X16H, ws16 + WTH, b_qkv, ws16);
    hipLaunchKernelGGL(k_attn_fused_mfma, dim3(3072), dim3(576), 0, stream,
                       ws16, ws16 + MASKH, table, pidx, ws16 + AOH);
    hipLaunchKernelGGL(k_out_gemm_mfma, dim3(288, 3), dim3(256), 0, stream,
                       ws16 + AOH, ws16 + WOTH, b_out, out);
}